// Round 8
// baseline (157.526 us; speedup 1.0000x reference)
//
#include <hip/hip_runtime.h>

// Navier-Stokes physics-informed loss (f32 in, scalar f32 out).
// x,y: (64,3,512,512). Interior: b in [1,62], i in [1,510], j in [1,510].
// r0 = |dudx + dvdy|
// r1 = |dudt + u*dudx + v*dudy + dpdx - MU*lap(u)|
// r2 = |dvdt + u*dvdx + v*dvdy + dpdy - MU*lap(v)|
// dudt = (u[b+1]-u[b-1])*32 ; d/dx,d/dy central *127.5 ; MU/DX^2 = 0.65025
//
// EMPIRICAL LAW from R1-R7 on this chip: resident waves ~ const/VGPR
// (occ: 32->75%, 40->55%, 64->41%, 76->29%; grid size irrelevant), and
// achieved HBM BW tracks resident waves (R1 @40VGPR/55%: 3.46 TB/s; all
// <=41% runs: 1.8-2.6). Byte-lean float4 (76 VGPR) loses more to the
// occupancy wall than it saves in bytes.
// R8 = R1's scalar-load structure (proven 40 VGPR, 3.46 TB/s) +
//   (a) m204 XCD swizzle ordered (b-chunk, j-half, i): each XCD owns 255
//       consecutive i-rows -> i+-1 refetch stays in its L2 (R1's 754MB
//       -> ~460MB, the R2 lesson), and
//   (b) f32 thread accumulators (R6-proven exact; -3 VGPR).

constexpr int Wd   = 512;
constexpr int CSTR = 512 * 512;
constexpr int BSTR = 3 * 512 * 512;

__global__ __launch_bounds__(256)
void ns_loss_kernel(const float* __restrict__ X, const float* __restrict__ Y,
                    const float* __restrict__ stdp, double* __restrict__ acc)
{
    const float s    = *stdp;
    const float idt  = 32.0f;          // applied to already-scaled centers
    const float sdx  = s * 127.5f;     // std / (2*DX), applied to raw loads
    const float slap = s * 0.65025f;   // std * MU / DX^2, applied to raw loads
    const float lap4 = 2.601f;         // 4 * MU/DX^2, applied to scaled center

    // m204 bijective XCD swizzle, nwg = 2040 = 8*255 (r=0).
    // Work-id ordering: z (b-chunk) major, then j-half, then i row.
    // XCD k owns 255 consecutive rows of one (z, j-half) -> i+-1 in-L2.
    const int orig = blockIdx.x;
    const int xcd  = orig & 7;
    const int wg   = xcd * 255 + (orig >> 3);
    const int z    = wg / 1020;        // b-chunk 0..1
    const int rem  = wg % 1020;
    const int jh   = rem / 510;        // j-half 0..1
    const int y    = rem % 510;        // i row 0..509

    const int tid   = threadIdx.x;
    const int tj    = jh * 256 + tid;  // 0..511
    const bool valid = (tj < 510);
    const int j  = 1 + (valid ? tj : 509);
    const int i  = 1 + y;              // 1..510
    const int b0 = 1 + 31 * z;         // 1 or 32; 31 b-steps each

    int c = b0 * BSTR + i * Wd + j;

    // register-carried scaled centers: u,v at b-1 and b, both tensors
    float xum = X[c - BSTR] * s,        xuc = X[c] * s;
    float xvm = X[c - BSTR + CSTR] * s, xvc = X[c + CSTR] * s;
    float yum = Y[c - BSTR] * s,        yuc = Y[c] * s;
    float yvm = Y[c - BSTR + CSTR] * s, yvc = Y[c + CSTR] * s;

    float s0 = 0.0f, s1 = 0.0f, s2 = 0.0f;

    for (int it = 0; it < 31; ++it) {
        // ---------------- X ----------------
        float up  = X[c + BSTR] * s;
        float vp  = X[c + BSTR + CSTR] * s;
        float uxp = X[c + Wd],          uxm = X[c - Wd];
        float uyp = X[c + 1],           uym = X[c - 1];
        float vxp = X[c + CSTR + Wd],   vxm = X[c + CSTR - Wd];
        float vyp = X[c + CSTR + 1],    vym = X[c + CSTR - 1];
        float pxp = X[c + 2*CSTR + Wd], pxm = X[c + 2*CSTR - Wd];
        float pyp = X[c + 2*CSTR + 1],  pym = X[c + 2*CSTR - 1];

        float dudx = (uxp - uxm) * sdx;
        float dudy = (uyp - uym) * sdx;
        float dvdx = (vxp - vxm) * sdx;
        float dvdy = (vyp - vym) * sdx;
        float lapu = (uxp + uxm + uyp + uym) * slap - lap4 * xuc;
        float lapv = (vxp + vxm + vyp + vym) * slap - lap4 * xvc;
        float r0x = fabsf(dudx + dvdy);
        float r1x = fabsf((up - xum) * idt + xuc * dudx + xvc * dudy
                          + (pxp - pxm) * sdx - lapu);
        float r2x = fabsf((vp - xvm) * idt + xuc * dvdx + xvc * dvdy
                          + (pyp - pym) * sdx - lapv);
        xum = xuc; xuc = up; xvm = xvc; xvc = vp;

        // ---------------- Y ----------------
        up  = Y[c + BSTR] * s;
        vp  = Y[c + BSTR + CSTR] * s;
        uxp = Y[c + Wd];          uxm = Y[c - Wd];
        uyp = Y[c + 1];           uym = Y[c - 1];
        vxp = Y[c + CSTR + Wd];   vxm = Y[c + CSTR - Wd];
        vyp = Y[c + CSTR + 1];    vym = Y[c + CSTR - 1];
        pxp = Y[c + 2*CSTR + Wd]; pxm = Y[c + 2*CSTR - Wd];
        pyp = Y[c + 2*CSTR + 1];  pym = Y[c + 2*CSTR - 1];

        float dudxY = (uxp - uxm) * sdx;
        float dudyY = (uyp - uym) * sdx;
        float dvdxY = (vxp - vxm) * sdx;
        float dvdyY = (vyp - vym) * sdx;
        float lapuY = (uxp + uxm + uyp + uym) * slap - lap4 * yuc;
        float lapvY = (vxp + vxm + vyp + vym) * slap - lap4 * yvc;
        float r0y = fabsf(dudxY + dvdyY);
        float r1y = fabsf((up - yum) * idt + yuc * dudxY + yvc * dudyY
                          + (pxp - pxm) * sdx - lapuY);
        float r2y = fabsf((vp - yvm) * idt + yuc * dvdxY + yvc * dvdyY
                          + (pyp - pym) * sdx - lapvY);
        yum = yuc; yuc = up; yvm = yvc; yvc = vp;

        const float e0 = r0y - r0x, e1 = r1y - r1x, e2 = r2y - r2x;
        if (valid) {
            s0 += e0 * e0;
            s1 += e1 * e1;
            s2 += e2 * e2;
        }
        c += BSTR;
    }

    // block reduction: f32 wave shuffle -> LDS -> f64 atomic per block
    for (int o = 32; o > 0; o >>= 1) {
        s0 += __shfl_down(s0, o);
        s1 += __shfl_down(s1, o);
        s2 += __shfl_down(s2, o);
    }
    __shared__ float sm[3][4];
    const int wid = threadIdx.x >> 6, lane = threadIdx.x & 63;
    if (lane == 0) { sm[0][wid] = s0; sm[1][wid] = s1; sm[2][wid] = s2; }
    __syncthreads();
    if (threadIdx.x == 0) {
        atomicAdd(&acc[0], (double)sm[0][0] + (double)sm[0][1]
                         + (double)sm[0][2] + (double)sm[0][3]);
        atomicAdd(&acc[1], (double)sm[1][0] + (double)sm[1][1]
                         + (double)sm[1][2] + (double)sm[1][3]);
        atomicAdd(&acc[2], (double)sm[2][0] + (double)sm[2][1]
                         + (double)sm[2][2] + (double)sm[2][3]);
    }
}

__global__ void ns_finalize_kernel(const double* __restrict__ acc,
                                   float* __restrict__ out)
{
    if (threadIdx.x == 0) {
        const double N = 62.0 * 510.0 * 510.0;
        out[0] = (float)(1.0e-3 * (acc[0] + acc[1] + acc[2]) / N);
    }
}

extern "C" void kernel_launch(void* const* d_in, const int* in_sizes, int n_in,
                              void* d_out, int out_size, void* d_ws, size_t ws_size,
                              hipStream_t stream) {
    const float* X    = (const float*)d_in[0];
    const float* Y    = (const float*)d_in[1];
    const float* stdp = (const float*)d_in[2];
    float* out  = (float*)d_out;
    double* acc = (double*)d_ws;

    hipMemsetAsync(acc, 0, 3 * sizeof(double), stream);

    dim3 block(256);
    dim3 grid(2040);   // = 2 b-chunks x 2 j-halves x 510 rows, XCD-swizzled
    ns_loss_kernel<<<grid, block, 0, stream>>>(X, Y, stdp, acc);
    ns_finalize_kernel<<<1, 64, 0, stream>>>(acc, out);
}

// Round 9
// 141.773 us; speedup vs baseline: 1.1111x; 1.1111x over previous
//
#include <hip/hip_runtime.h>

// Navier-Stokes physics-informed loss (f32 in, scalar f32 out).
// x,y: (64,3,512,512). Interior: b in [1,62], i in [1,510], j in [1,510].
// r0 = |dudx + dvdy| ; r1 = |dudt + u*dudx + v*dudy + dpdx - MU*lap u| ;
// r2 = |dvdt + u*dvdx + v*dvdy + dpdy - MU*lap v|
// dudt = (u[b+1]-u[b-1])*32 ; d/dx,d/dy central *127.5 ; MU/DX^2 = 0.65025
//
// MODEL (R1-R8): dur ~= requested_bytes / (7-10 TB/s cache-service ceiling).
// R1 1.83GB->223us, R7 1.17GB->167us, R8 1.83GB->183us. FETCH(HBM) already
// ~300MB (optimal). So: cut REQUESTED bytes.
// R9: 4-row i-blocking. Block = 512 thr = 4 rows x 128 float4-threads.
// Carried u,v centers (scaled) + loaded p centers go to LDS each b-step;
// interior rows read i+-1 from LDS; only band-edge rows (io=0/3) load one
// global neighbor row. Global: 9 -> avg 4.5 float4/thread/iter/tensor
// => requested ~0.66 GB (-44% vs R7).

constexpr int Wd   = 512;
constexpr int CSTR = 512 * 512;
constexpr int BSTR = 3 * 512 * 512;

__device__ __forceinline__ float4 ld4(const float* p) {
    return *reinterpret_cast<const float4*>(p);
}
__device__ __forceinline__ float4 scale4(float4 a, float s) {
    return make_float4(a.x * s, a.y * s, a.z * s, a.w * s);
}

// Residuals for one tensor at one b-step for this thread's 4 columns.
// uc,vc,um,vm,un,vn : SCALED centers (b, b-1, b+1). uu,ud,vu,vd : SCALED
// rows i+1 / i-1. pu,pd,pc : RAW p rows i+1 / i-1 / i.
__device__ __forceinline__ void residuals(
    const float* __restrict__ T, int c, int jt, float s, float sdx,
    float4 un, float4 vn, float4 uc, float4 vc, float4 um, float4 vm,
    float4 uu, float4 ud, float4 vu, float4 vd,
    float4 pu, float4 pd, float4 pc,
    float r0[4], float r1[4], float r2[4])
{
    float u_l = __shfl_up(uc.w, 1);
    float v_l = __shfl_up(vc.w, 1);
    float p_l = __shfl_up(pc.w, 1);
    float u_r = __shfl_down(uc.x, 1);
    float v_r = __shfl_down(vc.x, 1);
    float p_r = __shfl_down(pc.x, 1);
    if (jt == 64) {  // lane 0 of odd wave: needs col 255
        u_l = T[c - 1] * s;
        v_l = T[c + CSTR - 1] * s;
        p_l = T[c + 2 * CSTR - 1];
    }
    if (jt == 63) {  // lane 63 of even wave: needs col 256
        u_r = T[c + 4] * s;
        v_r = T[c + CSTR + 4] * s;
        p_r = T[c + 2 * CSTR + 4];
    }

    const float ucA[4] = {uc.x, uc.y, uc.z, uc.w};
    const float vcA[4] = {vc.x, vc.y, vc.z, vc.w};
    const float umA[4] = {um.x, um.y, um.z, um.w};
    const float vmA[4] = {vm.x, vm.y, vm.z, vm.w};
    const float unA[4] = {un.x, un.y, un.z, un.w};
    const float vnA[4] = {vn.x, vn.y, vn.z, vn.w};
    const float ul[4]  = {u_l, uc.x, uc.y, uc.z};
    const float ur[4]  = {uc.y, uc.z, uc.w, u_r};
    const float vl[4]  = {v_l, vc.x, vc.y, vc.z};
    const float vr[4]  = {vc.y, vc.z, vc.w, v_r};
    const float pl[4]  = {p_l, pc.x, pc.y, pc.z};
    const float pr[4]  = {pc.y, pc.z, pc.w, p_r};
    const float uuA[4] = {uu.x, uu.y, uu.z, uu.w};
    const float udA[4] = {ud.x, ud.y, ud.z, ud.w};
    const float vuA[4] = {vu.x, vu.y, vu.z, vu.w};
    const float vdA[4] = {vd.x, vd.y, vd.z, vd.w};
    const float puA[4] = {pu.x, pu.y, pu.z, pu.w};
    const float pdA[4] = {pd.x, pd.y, pd.z, pd.w};

    #pragma unroll
    for (int k = 0; k < 4; ++k) {
        const float dudx = (uuA[k] - udA[k]) * 127.5f;   // scaled inputs
        const float dvdx = (vuA[k] - vdA[k]) * 127.5f;
        const float dpdx = (puA[k] - pdA[k]) * sdx;      // raw p
        const float dudy = (ur[k] - ul[k]) * 127.5f;
        const float dvdy = (vr[k] - vl[k]) * 127.5f;
        const float dpdy = (pr[k] - pl[k]) * sdx;
        const float lapu = (uuA[k] + udA[k] + ur[k] + ul[k]) * 0.65025f
                         - 2.601f * ucA[k];
        const float lapv = (vuA[k] + vdA[k] + vr[k] + vl[k]) * 0.65025f
                         - 2.601f * vcA[k];
        r0[k] = fabsf(dudx + dvdy);
        r1[k] = fabsf((unA[k] - umA[k]) * 32.0f + ucA[k] * dudx + vcA[k] * dudy
                      + dpdx - lapu);
        r2[k] = fabsf((vnA[k] - vmA[k]) * 32.0f + ucA[k] * dvdx + vcA[k] * dvdy
                      + dpdy - lapv);
    }
}

__global__ __launch_bounds__(512)
void ns_loss_kernel(const float* __restrict__ X, const float* __restrict__ Y,
                    const float* __restrict__ stdp, double* __restrict__ acc)
{
    // [tensor][field u,v,p][row 0..3][j-float4]  = 48 KiB
    __shared__ float4 lds[2][3][4][128];
    __shared__ float sm[3][8];

    const float s   = *stdp;
    const float sdx = s * 127.5f;

    // Bijective XCD swizzle: nwg = 768 = 8*96 (r=0).
    const int orig = blockIdx.x;
    const int wg   = (orig & 7) * 96 + (orig >> 3);
    const int z    = wg / 128;           // b-chunk 0..5
    const int band = wg % 128;           // i-band 0..127 (4 rows each)

    const int tid = threadIdx.x;
    const int io  = tid >> 7;            // row within band, 0..3
    const int jt  = tid & 127;           // float4-column thread
    const int j0  = jt << 2;
    const int irow = 1 + band * 4 + io;  // 1..512 (511,512 only in band 127)
    const int i    = min(irow, 511);     // clamp: row 511 exists (boundary)
    const bool vrow = (irow <= 510);
    const int bs = 1 + 11 * z;
    const int nsteps = min(11, 62 - 11 * z);   // 11,11,11,11,11,7

    int c = bs * BSTR + i * Wd + j0;
    const int cup = (i < 511) ? Wd : 0;  // clamped +1-row offset

    // carried scaled centers (b-1, b) for u,v of both tensors
    float4 xum = scale4(ld4(X + c - BSTR), s);
    float4 xuc = scale4(ld4(X + c), s);
    float4 xvm = scale4(ld4(X + c - BSTR + CSTR), s);
    float4 xvc = scale4(ld4(X + c + CSTR), s);
    float4 yum = scale4(ld4(Y + c - BSTR), s);
    float4 yuc = scale4(ld4(Y + c), s);
    float4 yvm = scale4(ld4(Y + c - BSTR + CSTR), s);
    float4 yvc = scale4(ld4(Y + c + CSTR), s);

    float s0 = 0.0f, s1 = 0.0f, s2 = 0.0f;

    float4 xuN = make_float4(0,0,0,0), xvN = xuN, xpN = xuN;
    float4 yuN = xuN, yvN = xuN, ypN = xuN;

    for (int it = 0; it < nsteps; ++it) {
        // ---- global loads for this b-step ----
        const float4 xun = scale4(ld4(X + c + BSTR), s);
        const float4 xvn = scale4(ld4(X + c + BSTR + CSTR), s);
        const float4 yun = scale4(ld4(Y + c + BSTR), s);
        const float4 yvn = scale4(ld4(Y + c + BSTR + CSTR), s);
        const float4 xpc = ld4(X + c + 2 * CSTR);
        const float4 ypc = ld4(Y + c + 2 * CSTR);
        if (io == 0) {          // needs row i-1 from global (i-1 >= 0 always)
            xuN = scale4(ld4(X + c - Wd), s);
            xvN = scale4(ld4(X + c + CSTR - Wd), s);
            xpN = ld4(X + c + 2 * CSTR - Wd);
            yuN = scale4(ld4(Y + c - Wd), s);
            yvN = scale4(ld4(Y + c + CSTR - Wd), s);
            ypN = ld4(Y + c + 2 * CSTR - Wd);
        } else if (io == 3) {   // needs row i+1 from global (clamped)
            xuN = scale4(ld4(X + c + cup), s);
            xvN = scale4(ld4(X + c + CSTR + cup), s);
            xpN = ld4(X + c + 2 * CSTR + cup);
            yuN = scale4(ld4(Y + c + cup), s);
            yvN = scale4(ld4(Y + c + CSTR + cup), s);
            ypN = ld4(Y + c + 2 * CSTR + cup);
        }

        // ---- stage centers to LDS ----
        lds[0][0][io][jt] = xuc;  lds[0][1][io][jt] = xvc;  lds[0][2][io][jt] = xpc;
        lds[1][0][io][jt] = yuc;  lds[1][1][io][jt] = yvc;  lds[1][2][io][jt] = ypc;
        __syncthreads();

        // ---- gather i+-1 rows (LDS interior, global at band edges) ----
        float4 xud, xvd, xpd, yud, yvd, ypd;   // row i-1
        float4 xuu, xvu, xpu, yuu, yvu, ypu;   // row i+1
        if (io > 0) {
            xud = lds[0][0][io-1][jt]; xvd = lds[0][1][io-1][jt]; xpd = lds[0][2][io-1][jt];
            yud = lds[1][0][io-1][jt]; yvd = lds[1][1][io-1][jt]; ypd = lds[1][2][io-1][jt];
        } else { xud = xuN; xvd = xvN; xpd = xpN; yud = yuN; yvd = yvN; ypd = ypN; }
        if (io < 3) {
            xuu = lds[0][0][io+1][jt]; xvu = lds[0][1][io+1][jt]; xpu = lds[0][2][io+1][jt];
            yuu = lds[1][0][io+1][jt]; yvu = lds[1][1][io+1][jt]; ypu = lds[1][2][io+1][jt];
        } else { xuu = xuN; xvu = xvN; xpu = xpN; yuu = yuN; yvu = yvN; ypu = ypN; }

        // ---- residuals ----
        float r0x[4], r1x[4], r2x[4], r0y[4], r1y[4], r2y[4];
        residuals(X, c, jt, s, sdx, xun, xvn, xuc, xvc, xum, xvm,
                  xuu, xud, xvu, xvd, xpu, xpd, xpc, r0x, r1x, r2x);
        residuals(Y, c, jt, s, sdx, yun, yvn, yuc, yvc, yum, yvm,
                  yuu, yud, yvu, yvd, ypu, ypd, ypc, r0y, r1y, r2y);

        #pragma unroll
        for (int k = 0; k < 4; ++k) {
            float e0 = r0y[k] - r0x[k];
            float e1 = r1y[k] - r1x[k];
            float e2 = r2y[k] - r2x[k];
            const bool dead = (!vrow) || (k == 0 && j0 == 0)
                                      || (k == 3 && j0 == 508);
            if (dead) { e0 = 0.0f; e1 = 0.0f; e2 = 0.0f; }
            s0 += e0 * e0; s1 += e1 * e1; s2 += e2 * e2;
        }

        __syncthreads();   // all LDS reads done before next iter's writes

        // ---- advance carries ----
        xum = xuc; xuc = xun; xvm = xvc; xvc = xvn;
        yum = yuc; yuc = yun; yvm = yvc; yvc = yvn;
        c += BSTR;
    }

    // ---- reduction: wave shuffle -> LDS -> f64 atomic ----
    for (int o = 32; o > 0; o >>= 1) {
        s0 += __shfl_down(s0, o);
        s1 += __shfl_down(s1, o);
        s2 += __shfl_down(s2, o);
    }
    const int wid = tid >> 6, lane = tid & 63;
    if (lane == 0) { sm[0][wid] = s0; sm[1][wid] = s1; sm[2][wid] = s2; }
    __syncthreads();
    if (tid == 0) {
        double t0 = 0, t1 = 0, t2 = 0;
        #pragma unroll
        for (int w = 0; w < 8; ++w) {
            t0 += (double)sm[0][w]; t1 += (double)sm[1][w]; t2 += (double)sm[2][w];
        }
        atomicAdd(&acc[0], t0);
        atomicAdd(&acc[1], t1);
        atomicAdd(&acc[2], t2);
    }
}

__global__ void ns_finalize_kernel(const double* __restrict__ acc,
                                   float* __restrict__ out)
{
    if (threadIdx.x == 0) {
        const double N = 62.0 * 510.0 * 510.0;
        out[0] = (float)(1.0e-3 * (acc[0] + acc[1] + acc[2]) / N);
    }
}

extern "C" void kernel_launch(void* const* d_in, const int* in_sizes, int n_in,
                              void* d_out, int out_size, void* d_ws, size_t ws_size,
                              hipStream_t stream) {
    const float* X    = (const float*)d_in[0];
    const float* Y    = (const float*)d_in[1];
    const float* stdp = (const float*)d_in[2];
    float* out  = (float*)d_out;
    double* acc = (double*)d_ws;

    hipMemsetAsync(acc, 0, 3 * sizeof(double), stream);

    dim3 block(512);
    dim3 grid(128 * 6);   // 128 i-bands x 6 b-chunks = 768 blocks (3/CU)
    ns_loss_kernel<<<grid, block, 0, stream>>>(X, Y, stdp, acc);
    ns_finalize_kernel<<<1, 64, 0, stream>>>(acc, out);
}